// Round 10
// baseline (246.642 us; speedup 1.0000x reference)
//
#include <hip/hip_runtime.h>
#include <hip/hip_bf16.h>

typedef __attribute__((ext_vector_type(8))) short bf16x8;   // 8 bf16 (4 VGPRs)
typedef __attribute__((ext_vector_type(4))) float f32x4;    // MFMA C/D

#define KTOT 9216   // 1024 (gelu part) + 1024*8 (spline bases part)
#define KHALF 4608  // split-K slice
#define NB   8192
#define NIN  1024
#define NOUT 1024

__device__ __forceinline__ void load_lds16(const void* g, void* l) {
  __builtin_amdgcn_global_load_lds(
      (const __attribute__((address_space(1))) void*)g,
      (__attribute__((address_space(3))) void*)l, 16, 0, 0);
}

// ---------------------------------------------------------------------------
// Kernel 1 (merged prep): blocks [0,4096) build A; blocks [4096,8704) pack W.
// ---------------------------------------------------------------------------
__global__ void prep(const float* __restrict__ x,
                     const float* __restrict__ grid,
                     __hip_bfloat16* __restrict__ A,
                     const float* __restrict__ bw,
                     const float* __restrict__ sw,
                     __hip_bfloat16* __restrict__ W) {
  if (blockIdx.x < 4096) {
    const int tid = blockIdx.x * blockDim.x + threadIdx.x;
    const int i  = tid & (NIN - 1);
    const int b0 = (tid >> 10) << 3;                       // 8 rows / thread

    float g[12];
#pragma unroll
    for (int j = 0; j < 12; ++j) g[j] = grid[j];

    float invdr1[10], invdd1[10], invdr2[9], invdd2[9], invdr3[8], invdd3[8];
#pragma unroll
    for (int j = 0; j < 10; ++j) {
      invdr1[j] = __builtin_amdgcn_rcpf(g[j + 1] - g[j]);
      invdd1[j] = __builtin_amdgcn_rcpf(g[j + 2] - g[j + 1]);
    }
#pragma unroll
    for (int j = 0; j < 9; ++j) {
      invdr2[j] = __builtin_amdgcn_rcpf(g[j + 2] - g[j]);
      invdd2[j] = __builtin_amdgcn_rcpf(g[j + 3] - g[j + 1]);
    }
#pragma unroll
    for (int j = 0; j < 8; ++j) {
      invdr3[j] = __builtin_amdgcn_rcpf(g[j + 3] - g[j]);
      invdd3[j] = __builtin_amdgcn_rcpf(g[j + 4] - g[j + 1]);
    }

    for (int bb = 0; bb < 8; ++bb) {
      const int b = b0 + bb;
      const float xv = x[(size_t)b * NIN + i];
      const float ge = 0.5f * xv * (1.0f + erff(xv * 0.70710678118654752f));
      __hip_bfloat16* Arow = A + (size_t)b * KTOT;
      Arow[i] = __float2bfloat16(ge);

      float bas[11];
#pragma unroll
      for (int j = 0; j < 11; ++j)
        bas[j] = (xv >= g[j] && xv < g[j + 1]) ? 1.0f : 0.0f;
#pragma unroll
      for (int j = 0; j < 10; ++j)
        bas[j] = (xv - g[j]) * invdr1[j] * bas[j] + (g[j + 2] - xv) * invdd1[j] * bas[j + 1];
#pragma unroll
      for (int j = 0; j < 9; ++j)
        bas[j] = (xv - g[j]) * invdr2[j] * bas[j] + (g[j + 3] - xv) * invdd2[j] * bas[j + 1];
#pragma unroll
      for (int j = 0; j < 8; ++j)
        bas[j] = (xv - g[j]) * invdr3[j] * bas[j] + (g[j + 4] - xv) * invdd3[j] * bas[j + 1];

      union { __hip_bfloat16 h[8]; uint4 v; } u;
#pragma unroll
      for (int k = 0; k < 8; ++k) u.h[k] = __float2bfloat16(bas[k]);
      *reinterpret_cast<uint4*>(Arow + NIN + i * 8) = u.v;
    }
  } else {
    const int idx = (blockIdx.x - 4096) * blockDim.x + threadIdx.x;
    const int o  = idx / 1152;
    const int c8 = (idx - o * 1152) * 8;
    const float* src = (c8 < 1024) ? (bw + (size_t)o * 1024 + c8)
                                   : (sw + (size_t)o * 8192 + (c8 - 1024));
    float4 f0 = reinterpret_cast<const float4*>(src)[0];
    float4 f1 = reinterpret_cast<const float4*>(src)[1];
    union { __hip_bfloat16 h[8]; uint4 v; } u;
    u.h[0] = __float2bfloat16(f0.x); u.h[1] = __float2bfloat16(f0.y);
    u.h[2] = __float2bfloat16(f0.z); u.h[3] = __float2bfloat16(f0.w);
    u.h[4] = __float2bfloat16(f1.x); u.h[5] = __float2bfloat16(f1.y);
    u.h[6] = __float2bfloat16(f1.z); u.h[7] = __float2bfloat16(f1.w);
    *reinterpret_cast<uint4*>(W + (size_t)o * KTOT + c8) = u.v;
  }
}

// ---------------------------------------------------------------------------
// Kernel 2: flatmm GEMM — A staged via LDS (ring-4, XOR-swizzled), B streamed
// global->registers (wave-private, double-buffered even/odd). 256x256 tile,
// BK=64, split-K=2, 8 waves (2M x 4N), per-wave 128x64.
// One barrier per tile. Per tile T:
//   P1: RD_A(half0) [8 ds_read, cross barrier]; LOADB(B(T+1)) [4 dwordx4];
//       vmcnt(8); s_barrier; lgkmcnt(0); sched_barrier; MFMA half0 x32
//   P2: RD_A(half1); stageA(T+3) [4 gload_lds, post-barrier];
//       lgkmcnt(0); sched_barrier; MFMA half1 x32
// Drain audit (steady): gate(T) = vmcnt(8) leaves {stageA(T+2), B(T+1)},
// drains B(T) (needed by MFMA(T)) and stageA(T+1) (published at barrier(T),
// read pre-barrier at T+1 -> one barrier early, safe). Stage writes issue
// post-barrier(T) targeting buf (T+3)&3, whose last readers (tile T-1)
// retired their ds_reads before passing barrier(T). Prologue
// {sA0,sA1,B0,sA2}+vmcnt(12); tail gates 8/8/4/0.
// ---------------------------------------------------------------------------
__global__ __launch_bounds__(512, 2)
void gemm_flat(const __hip_bfloat16* __restrict__ A,
               const __hip_bfloat16* __restrict__ Bw,
               float* __restrict__ P0,
               float* __restrict__ P1w) {
  __shared__ char smem[131072];   // A ring-4: [4 buf][2 half][64 rows][128 B]

  const int tid  = threadIdx.x;
  const int lane = tid & 63;
  const int wave = tid >> 6;
  const int wr = wave >> 2;          // 0..1 -> M half (128 rows)
  const int wc = wave & 3;           // 0..3 -> N quarter (64 cols)

  const int orig = blockIdx.x;                    // 256 blocks
  const int bid  = (orig & 7) * 32 + (orig >> 3); // bijective XCD chunking
  const int ks    = bid & 1;                      // K slice
  const int tileN = (bid >> 1) & 3;               // 4 N tiles
  const int tileM = bid >> 3;                     // 32 M tiles
  const size_t brow = (size_t)tileM * 256;
  const size_t bcol = (size_t)tileN * 256;
  const int kbeg = ks * KHALF;

  const __hip_bfloat16* Ab = A  + brow * KTOT;
  float* C = ks ? P1w : P0;

  // ---- A staging (pre-swizzled global source, linear LDS dest) ----
  const int swsrc = ((tid & 7) ^ ((tid >> 3) & 7)) * 8;
  const __hip_bfloat16* srcA = Ab + (size_t)(tid >> 3) * KTOT + kbeg + swsrc;
  const int wdst = wave * 1024;

  auto stageA = [&](int kt) {                       // stages all 256 rows, tile kt
    const __hip_bfloat16* g = srcA + (size_t)kt * 64;
    char* d = smem + ((kt & 3) * 32768) + wdst;
    load_lds16(g, d);                               // rows   0- 63
    load_lds16(g + (size_t)64  * KTOT, d + 8192);   // rows  64-127
    load_lds16(g + (size_t)128 * KTOT, d + 16384);  // rows 128-191
    load_lds16(g + (size_t)192 * KTOT, d + 24576);  // rows 192-255
  };

  // ---- fragment read addressing (XOR term is a per-lane constant) ----
  const int fr = lane & 15;
  const int hi = lane >> 4;                      // 0..3 -> k-slot within 32
  const int sw = (fr & 7) << 4;
  const int ax0 = (hi * 16) ^ sw;                // kk=0 slot byte
  const int ax1 = (64 + hi * 16) ^ sw;           // kk=1 slot byte

  // ---- B per-lane global pointers (wave-private fragments) ----
  // b[n][kk] holds B[col = bcol + wc*64 + n*16 + fr][k = kbeg + kt*64 + kk*32 + hi*8 + e]
  const __hip_bfloat16* pB0 = Bw + (size_t)(bcol + wc * 64 + fr) * KTOT + kbeg + hi * 8;
  const __hip_bfloat16* pB1 = pB0 + (size_t)16 * KTOT;
  const __hip_bfloat16* pB2 = pB0 + (size_t)32 * KTOT;
  const __hip_bfloat16* pB3 = pB0 + (size_t)48 * KTOT;

  bf16x8 a[4][2], bE[4][2], bO[4][2];
  f32x4 acc[8][4] = {};

#define LOADB(DST) do { \
    DST[0][0] = *(const bf16x8*)(pB0); DST[0][1] = *(const bf16x8*)(pB0 + 32); \
    DST[1][0] = *(const bf16x8*)(pB1); DST[1][1] = *(const bf16x8*)(pB1 + 32); \
    DST[2][0] = *(const bf16x8*)(pB2); DST[2][1] = *(const bf16x8*)(pB2 + 32); \
    DST[3][0] = *(const bf16x8*)(pB3); DST[3][1] = *(const bf16x8*)(pB3 + 32); \
    pB0 += 64; pB1 += 64; pB2 += 64; pB3 += 64; } while (0)

#define RD_A(BUF, MH) { \
    const char* Ah = smem + (BUF) * 32768 + wr * 16384 + (MH) * 8192; \
    _Pragma("unroll") \
    for (int mi2 = 0; mi2 < 4; ++mi2) { \
      const char* p = Ah + (mi2 * 16 + fr) * 128; \
      a[mi2][0] = *(const bf16x8*)(p + ax0); \
      a[mi2][1] = *(const bf16x8*)(p + ax1); } }

#define MFMA_HALF(MH, CUR) do { \
    __builtin_amdgcn_s_setprio(1); \
    _Pragma("unroll") \
    for (int mi2 = 0; mi2 < 4; ++mi2) \
      _Pragma("unroll") \
      for (int ni2 = 0; ni2 < 4; ++ni2) \
        _Pragma("unroll") \
        for (int kk = 0; kk < 2; ++kk) \
          acc[(MH) * 4 + mi2][ni2] = \
            __builtin_amdgcn_mfma_f32_16x16x32_bf16(a[mi2][kk], CUR[ni2][kk], \
                                                    acc[(MH) * 4 + mi2][ni2], 0, 0, 0); \
    __builtin_amdgcn_s_setprio(0); } while (0)

#define TILE(BUF, CUR, NXT, DOB, STA, KT3, VM) do { \
    /* P1 */ \
    RD_A(BUF, 0); \
    if (DOB) LOADB(NXT); \
    asm volatile(VM ::: "memory"); \
    __builtin_amdgcn_s_barrier(); \
    asm volatile("s_waitcnt lgkmcnt(0)" ::: "memory"); \
    __builtin_amdgcn_sched_barrier(0); \
    MFMA_HALF(0, CUR); \
    /* P2 */ \
    RD_A(BUF, 1); \
    if (STA) stageA(KT3); \
    asm volatile("s_waitcnt lgkmcnt(0)" ::: "memory"); \
    __builtin_amdgcn_sched_barrier(0); \
    MFMA_HALF(1, CUR); \
  } while (0)

  // prologue: sA(0), sA(1), B(0), sA(2); drain sA(0); publish at barrier.
  stageA(0);
  stageA(1);
  LOADB(bE);          // B(0); pointers now at kt=1
  stageA(2);
  asm volatile("s_waitcnt vmcnt(12)" ::: "memory");
  __builtin_amdgcn_s_barrier();
  asm volatile("" ::: "memory");

  // main: tiles 0..67 (17 x 4), steady vmcnt(8)
  for (int it = 0; it < 17; ++it) {
    const int t0 = it * 4;
    TILE(0, bE, bO, 1, 1, t0 + 3, "s_waitcnt vmcnt(8)");
    TILE(1, bO, bE, 1, 1, t0 + 4, "s_waitcnt vmcnt(8)");
    TILE(2, bE, bO, 1, 1, t0 + 5, "s_waitcnt vmcnt(8)");
    TILE(3, bO, bE, 1, 1, t0 + 6, "s_waitcnt vmcnt(8)");
  }
  // tail: tiles 68..71 (last stage = sA(71) at T=68; last B = B(71) at T=70)
  TILE(0, bE, bO, 1, 1, 71, "s_waitcnt vmcnt(8)");
  TILE(1, bO, bE, 1, 0, 0,  "s_waitcnt vmcnt(8)");
  TILE(2, bE, bO, 1, 0, 0,  "s_waitcnt vmcnt(4)");
  TILE(3, bO, bE, 0, 0, 0,  "s_waitcnt vmcnt(0)");

#undef TILE
#undef MFMA_HALF
#undef RD_A
#undef LOADB

  // epilogue: C/D layout col = lane&15, row = (lane>>4)*4 + reg
  const int crow0 = (lane >> 4) * 4;
#pragma unroll
  for (int mi = 0; mi < 8; ++mi)
#pragma unroll
    for (int ni = 0; ni < 4; ++ni) {
      const size_t r0 = brow + wr * 128 + mi * 16 + crow0;
      const size_t cc = bcol + wc * 64 + ni * 16 + fr;
      float* cp = C + r0 * NOUT + cc;
#pragma unroll
      for (int r = 0; r < 4; ++r) cp[(size_t)r * NOUT] = acc[mi][ni][r];
    }
}

// ---------------------------------------------------------------------------
// Kernel 3: y = P0 + P1 (split-K reduce), rowwise LayerNorm + PReLU -> y.
// P1 aliases d_out. One block per row.
// ---------------------------------------------------------------------------
__global__ void reduce_ln_prelu(const float* __restrict__ P0,
                                float* __restrict__ y,
                                const float* __restrict__ gamma,
                                const float* __restrict__ beta,
                                const float* __restrict__ pa) {
  const int row = blockIdx.x;
  const int t = threadIdx.x;                 // 256 threads, 4 floats each
  const float* p0r = P0 + (size_t)row * NOUT;
  float* yr = y + (size_t)row * NOUT;

  float4 aa = reinterpret_cast<const float4*>(p0r)[t];
  float4 v = reinterpret_cast<const float4*>(yr)[t];
  v.x += aa.x; v.y += aa.y; v.z += aa.z; v.w += aa.w;

  float s  = v.x + v.y + v.z + v.w;
  float sq = v.x * v.x + v.y * v.y + v.z * v.z + v.w * v.w;
#pragma unroll
  for (int off = 32; off > 0; off >>= 1) {
    s  += __shfl_down(s, off);
    sq += __shfl_down(sq, off);
  }
  __shared__ float red[8];
  const int wv = t >> 6, lane = t & 63;
  if (lane == 0) { red[wv] = s; red[4 + wv] = sq; }
  __syncthreads();
  if (t == 0) {
    const float S = red[0] + red[1] + red[2] + red[3];
    const float Q = red[4] + red[5] + red[6] + red[7];
    const float mu = S * (1.0f / NOUT);
    const float var = Q * (1.0f / NOUT) - mu * mu;
    red[0] = mu;
    red[1] = rsqrtf(var + 1e-5f);
  }
  __syncthreads();
  const float mu = red[0], rs = red[1];
  const float aP = pa[0];
  const float4 g4 = reinterpret_cast<const float4*>(gamma)[t];
  const float4 b4 = reinterpret_cast<const float4*>(beta)[t];
  float o0 = (v.x - mu) * rs * g4.x + b4.x;
  float o1 = (v.y - mu) * rs * g4.y + b4.y;
  float o2 = (v.z - mu) * rs * g4.z + b4.z;
  float o3 = (v.w - mu) * rs * g4.w + b4.w;
  v.x = o0 >= 0.0f ? o0 : aP * o0;
  v.y = o1 >= 0.0f ? o1 : aP * o1;
  v.z = o2 >= 0.0f ? o2 : aP * o2;
  v.w = o3 >= 0.0f ? o3 : aP * o3;
  reinterpret_cast<float4*>(yr)[t] = v;
}

// ---------------------------------------------------------------------------
extern "C" void kernel_launch(void* const* d_in, const int* in_sizes, int n_in,
                              void* d_out, int out_size, void* d_ws, size_t ws_size,
                              hipStream_t stream) {
  const float* x     = (const float*)d_in[0];
  const float* bw    = (const float*)d_in[1];
  const float* sw    = (const float*)d_in[2];
  const float* grid  = (const float*)d_in[3];
  const float* gamma = (const float*)d_in[4];
  const float* beta  = (const float*)d_in[5];
  const float* pa    = (const float*)d_in[6];
  float* out = (float*)d_out;

  __hip_bfloat16* Abuf = (__hip_bfloat16*)d_ws;                 // 8192 x 9216 bf16
  __hip_bfloat16* Wbuf = Abuf + (size_t)NB * KTOT;              // 1024 x 9216 bf16
  float* P0 = (float*)(Wbuf + (size_t)NOUT * KTOT);             // 8192 x 1024 f32

  prep<<<4096 + 4608, 256, 0, stream>>>(x, grid, Abuf, bw, sw, Wbuf);
  gemm_flat<<<(NB / 256) * (NOUT / 256) * 2, 512, 0, stream>>>(Abuf, Wbuf, P0, out);
  reduce_ln_prelu<<<NB, 256, 0, stream>>>(P0, out, gamma, beta, pa);
}

// Round 11
// 207.278 us; speedup vs baseline: 1.1899x; 1.1899x over previous
//
#include <hip/hip_runtime.h>
#include <hip/hip_bf16.h>

typedef __attribute__((ext_vector_type(8))) short bf16x8;   // 8 bf16 (4 VGPRs)
typedef __attribute__((ext_vector_type(4))) float f32x4;    // MFMA C/D

#define KTOT 9216   // 1024 (gelu part) + 1024*8 (spline bases part)
#define KHALF 4608  // split-K slice
#define NB   8192
#define NIN  1024
#define NOUT 1024

__device__ __forceinline__ void load_lds16(const void* g, void* l) {
  __builtin_amdgcn_global_load_lds(
      (const __attribute__((address_space(1))) void*)g,
      (__attribute__((address_space(3))) void*)l, 16, 0, 0);
}

// ---------------------------------------------------------------------------
// Kernel 1 (merged prep): blocks [0,4096) build A; blocks [4096,8704) pack W
// into FLAT (MFMA-fragment-ordered) layout:
//   Wflat 16B-chunk idx = ((c*144 + t)*8 + n*2 + kk)*64 + lane, holding
//   W[col = c*64 + n*16 + (lane&15)][k = t*64 + kk*32 + (lane>>4)*8 + 0..7].
// GEMM's LOADB then reads 1024 contiguous bytes per wave per instruction.
// ---------------------------------------------------------------------------
__global__ void prep(const float* __restrict__ x,
                     const float* __restrict__ grid,
                     __hip_bfloat16* __restrict__ A,
                     const float* __restrict__ bw,
                     const float* __restrict__ sw,
                     __hip_bfloat16* __restrict__ W) {
  if (blockIdx.x < 4096) {
    const int tid = blockIdx.x * blockDim.x + threadIdx.x;
    const int i  = tid & (NIN - 1);
    const int b0 = (tid >> 10) << 3;                       // 8 rows / thread

    float g[12];
#pragma unroll
    for (int j = 0; j < 12; ++j) g[j] = grid[j];

    float invdr1[10], invdd1[10], invdr2[9], invdd2[9], invdr3[8], invdd3[8];
#pragma unroll
    for (int j = 0; j < 10; ++j) {
      invdr1[j] = __builtin_amdgcn_rcpf(g[j + 1] - g[j]);
      invdd1[j] = __builtin_amdgcn_rcpf(g[j + 2] - g[j + 1]);
    }
#pragma unroll
    for (int j = 0; j < 9; ++j) {
      invdr2[j] = __builtin_amdgcn_rcpf(g[j + 2] - g[j]);
      invdd2[j] = __builtin_amdgcn_rcpf(g[j + 3] - g[j + 1]);
    }
#pragma unroll
    for (int j = 0; j < 8; ++j) {
      invdr3[j] = __builtin_amdgcn_rcpf(g[j + 3] - g[j]);
      invdd3[j] = __builtin_amdgcn_rcpf(g[j + 4] - g[j + 1]);
    }

    for (int bb = 0; bb < 8; ++bb) {
      const int b = b0 + bb;
      const float xv = x[(size_t)b * NIN + i];
      const float ge = 0.5f * xv * (1.0f + erff(xv * 0.70710678118654752f));
      __hip_bfloat16* Arow = A + (size_t)b * KTOT;
      Arow[i] = __float2bfloat16(ge);

      float bas[11];
#pragma unroll
      for (int j = 0; j < 11; ++j)
        bas[j] = (xv >= g[j] && xv < g[j + 1]) ? 1.0f : 0.0f;
#pragma unroll
      for (int j = 0; j < 10; ++j)
        bas[j] = (xv - g[j]) * invdr1[j] * bas[j] + (g[j + 2] - xv) * invdd1[j] * bas[j + 1];
#pragma unroll
      for (int j = 0; j < 9; ++j)
        bas[j] = (xv - g[j]) * invdr2[j] * bas[j] + (g[j + 3] - xv) * invdd2[j] * bas[j + 1];
#pragma unroll
      for (int j = 0; j < 8; ++j)
        bas[j] = (xv - g[j]) * invdr3[j] * bas[j] + (g[j + 4] - xv) * invdd3[j] * bas[j + 1];

      union { __hip_bfloat16 h[8]; uint4 v; } u;
#pragma unroll
      for (int k = 0; k < 8; ++k) u.h[k] = __float2bfloat16(bas[k]);
      *reinterpret_cast<uint4*>(Arow + NIN + i * 8) = u.v;
    }
  } else {
    const int idx = (blockIdx.x - 4096) * blockDim.x + threadIdx.x; // 0..1179647
    const int ln  = idx & 63;
    const int blk = idx >> 6;
    const int kk  = blk & 1;
    const int n   = (blk >> 1) & 3;
    const int t   = (blk >> 3) % 144;
    const int c   = blk / 1152;
    const int col = c * 64 + n * 16 + (ln & 15);
    const int k   = t * 64 + kk * 32 + (ln >> 4) * 8;
    const float* src = (k < 1024) ? (bw + (size_t)col * 1024 + k)
                                  : (sw + (size_t)col * 8192 + (k - 1024));
    float4 f0 = reinterpret_cast<const float4*>(src)[0];
    float4 f1 = reinterpret_cast<const float4*>(src)[1];
    union { __hip_bfloat16 h[8]; uint4 v; } u;
    u.h[0] = __float2bfloat16(f0.x); u.h[1] = __float2bfloat16(f0.y);
    u.h[2] = __float2bfloat16(f0.z); u.h[3] = __float2bfloat16(f0.w);
    u.h[4] = __float2bfloat16(f1.x); u.h[5] = __float2bfloat16(f1.y);
    u.h[6] = __float2bfloat16(f1.z); u.h[7] = __float2bfloat16(f1.w);
    *reinterpret_cast<uint4*>(W + (size_t)idx * 8) = u.v;
  }
}

// ---------------------------------------------------------------------------
// Kernel 2: flatmm GEMM — A via LDS ring-4 (XOR-swizzled), B streamed
// global->registers from PRE-SHUFFLED flat layout (coalesced: 1024 B/wave
// per instruction). 256x256 tile, BK=64, split-K=2, 8 waves (2M x 4N).
// One barrier per tile. Per tile T:
//   P1: RD_A(half0); LOADB(B(T+1)) [8 coalesced dwordx4]; vmcnt; barrier;
//       lgkmcnt(0); sched_barrier; MFMA half0 x32
//   P2: RD_A(half1); stageA(T+3) [post-barrier]; lgkmcnt(0); sched_barrier;
//       MFMA half1 x32
// Gate audit (pool at P1(T) after LOADB = {sA(T+1)4, B(T)8, sA(T+2)4,
// B(T+1)8}): vmcnt(12) keeps {sA(T+2), B(T+1)}, drains B(T) (needed by
// MFMA(T)) + sA(T+1) (published at barrier(T)) — minimal correct gate.
// Prologue {sA0,sA1,B0,sA2} + vmcnt(16) (drains sA0 only).
// Tail: T=68,69 vm(12); T=70 vm(8); T=71 vm(0).
// ---------------------------------------------------------------------------
__global__ __launch_bounds__(512, 2)
void gemm_flat(const __hip_bfloat16* __restrict__ A,
               const __hip_bfloat16* __restrict__ Bw,
               float* __restrict__ P0,
               float* __restrict__ P1w) {
  __shared__ char smem[131072];   // A ring-4: [4 buf][2 half][64 rows][128 B]

  const int tid  = threadIdx.x;
  const int lane = tid & 63;
  const int wave = tid >> 6;
  const int wr = wave >> 2;          // 0..1 -> M half (128 rows)
  const int wc = wave & 3;           // 0..3 -> N quarter (64 cols)

  const int orig = blockIdx.x;                    // 256 blocks
  const int bid  = (orig & 7) * 32 + (orig >> 3); // bijective XCD chunking
  const int ks    = bid & 1;                      // K slice
  const int tileN = (bid >> 1) & 3;               // 4 N tiles
  const int tileM = bid >> 3;                     // 32 M tiles
  const size_t brow = (size_t)tileM * 256;
  const size_t bcol = (size_t)tileN * 256;
  const int kbeg = ks * KHALF;

  const __hip_bfloat16* Ab = A + brow * KTOT;
  float* C = ks ? P1w : P0;

  // ---- A staging (pre-swizzled global source, linear LDS dest) ----
  const int swsrc = ((tid & 7) ^ ((tid >> 3) & 7)) * 8;
  const __hip_bfloat16* srcA = Ab + (size_t)(tid >> 3) * KTOT + kbeg + swsrc;
  const int wdst = wave * 1024;

  auto stageA = [&](int kt) {                       // stages all 256 rows, tile kt
    const __hip_bfloat16* g = srcA + (size_t)kt * 64;
    char* d = smem + ((kt & 3) * 32768) + wdst;
    load_lds16(g, d);                               // rows   0- 63
    load_lds16(g + (size_t)64  * KTOT, d + 8192);   // rows  64-127
    load_lds16(g + (size_t)128 * KTOT, d + 16384);  // rows 128-191
    load_lds16(g + (size_t)192 * KTOT, d + 24576);  // rows 192-255
  };

  // ---- fragment read addressing (XOR term is a per-lane constant) ----
  const int fr = lane & 15;
  const int hi = lane >> 4;                      // 0..3 -> k-slot within 32
  const int sw = (fr & 7) << 4;
  const int ax0 = (hi * 16) ^ sw;                // kk=0 slot byte
  const int ax1 = (64 + hi * 16) ^ sw;           // kk=1 slot byte

  // ---- B: flat-layout streaming pointer (wave block = tileN*4 + wc) ----
  const __hip_bfloat16* pB =
      Bw + ((size_t)(tileN * 4 + wc) * 144 + (size_t)ks * 72) * 4096 + lane * 8;

  bf16x8 a[4][2], bE[4][2], bO[4][2];
  f32x4 acc[8][4] = {};

#define LOADB(DST) do { \
    DST[0][0] = *(const bf16x8*)(pB);        DST[0][1] = *(const bf16x8*)(pB + 512); \
    DST[1][0] = *(const bf16x8*)(pB + 1024); DST[1][1] = *(const bf16x8*)(pB + 1536); \
    DST[2][0] = *(const bf16x8*)(pB + 2048); DST[2][1] = *(const bf16x8*)(pB + 2560); \
    DST[3][0] = *(const bf16x8*)(pB + 3072); DST[3][1] = *(const bf16x8*)(pB + 3584); \
    pB += 4096; } while (0)

#define RD_A(BUF, MH) { \
    const char* Ah = smem + (BUF) * 32768 + wr * 16384 + (MH) * 8192; \
    _Pragma("unroll") \
    for (int mi2 = 0; mi2 < 4; ++mi2) { \
      const char* p = Ah + (mi2 * 16 + fr) * 128; \
      a[mi2][0] = *(const bf16x8*)(p + ax0); \
      a[mi2][1] = *(const bf16x8*)(p + ax1); } }

#define MFMA_HALF(MH, CUR) do { \
    __builtin_amdgcn_s_setprio(1); \
    _Pragma("unroll") \
    for (int mi2 = 0; mi2 < 4; ++mi2) \
      _Pragma("unroll") \
      for (int ni2 = 0; ni2 < 4; ++ni2) \
        _Pragma("unroll") \
        for (int kk = 0; kk < 2; ++kk) \
          acc[(MH) * 4 + mi2][ni2] = \
            __builtin_amdgcn_mfma_f32_16x16x32_bf16(a[mi2][kk], CUR[ni2][kk], \
                                                    acc[(MH) * 4 + mi2][ni2], 0, 0, 0); \
    __builtin_amdgcn_s_setprio(0); } while (0)

#define TILE(BUF, CUR, NXT, DOB, STA, KT3, VM) do { \
    /* P1 */ \
    RD_A(BUF, 0); \
    if (DOB) LOADB(NXT); \
    asm volatile(VM ::: "memory"); \
    __builtin_amdgcn_s_barrier(); \
    asm volatile("s_waitcnt lgkmcnt(0)" ::: "memory"); \
    __builtin_amdgcn_sched_barrier(0); \
    MFMA_HALF(0, CUR); \
    /* P2 */ \
    RD_A(BUF, 1); \
    if (STA) stageA(KT3); \
    asm volatile("s_waitcnt lgkmcnt(0)" ::: "memory"); \
    __builtin_amdgcn_sched_barrier(0); \
    MFMA_HALF(1, CUR); \
  } while (0)

  // prologue: sA(0), sA(1), B(0), sA(2); vmcnt(16) drains sA(0); publish.
  stageA(0);
  stageA(1);
  LOADB(bE);          // B(0); pB now at tile 1
  stageA(2);
  asm volatile("s_waitcnt vmcnt(16)" ::: "memory");
  __builtin_amdgcn_s_barrier();
  asm volatile("" ::: "memory");

  // main: tiles 0..67 (17 x 4), steady vmcnt(12)
  for (int it = 0; it < 17; ++it) {
    const int t0 = it * 4;
    TILE(0, bE, bO, 1, 1, t0 + 3, "s_waitcnt vmcnt(12)");
    TILE(1, bO, bE, 1, 1, t0 + 4, "s_waitcnt vmcnt(12)");
    TILE(2, bE, bO, 1, 1, t0 + 5, "s_waitcnt vmcnt(12)");
    TILE(3, bO, bE, 1, 1, t0 + 6, "s_waitcnt vmcnt(12)");
  }
  // tail: T=68 stages sA(71); T=70 loads B(71); derived gates 12/12/8/0
  TILE(0, bE, bO, 1, 1, 71, "s_waitcnt vmcnt(12)");
  TILE(1, bO, bE, 1, 0, 0,  "s_waitcnt vmcnt(12)");
  TILE(2, bE, bO, 1, 0, 0,  "s_waitcnt vmcnt(8)");
  TILE(3, bO, bE, 0, 0, 0,  "s_waitcnt vmcnt(0)");

#undef TILE
#undef MFMA_HALF
#undef RD_A
#undef LOADB

  // epilogue: C/D layout col = lane&15, row = (lane>>4)*4 + reg
  const int crow0 = (lane >> 4) * 4;
#pragma unroll
  for (int mi = 0; mi < 8; ++mi)
#pragma unroll
    for (int ni = 0; ni < 4; ++ni) {
      const size_t r0 = brow + wr * 128 + mi * 16 + crow0;
      const size_t cc = bcol + wc * 64 + ni * 16 + fr;
      float* cp = C + r0 * NOUT + cc;
#pragma unroll
      for (int r = 0; r < 4; ++r) cp[(size_t)r * NOUT] = acc[mi][ni][r];
    }
}

// ---------------------------------------------------------------------------
// Kernel 3: y = P0 + P1 (split-K reduce), rowwise LayerNorm + PReLU -> y.
// P1 aliases d_out. One block per row.
// ---------------------------------------------------------------------------
__global__ void reduce_ln_prelu(const float* __restrict__ P0,
                                float* __restrict__ y,
                                const float* __restrict__ gamma,
                                const float* __restrict__ beta,
                                const float* __restrict__ pa) {
  const int row = blockIdx.x;
  const int t = threadIdx.x;                 // 256 threads, 4 floats each
  const float* p0r = P0 + (size_t)row * NOUT;
  float* yr = y + (size_t)row * NOUT;

  float4 aa = reinterpret_cast<const float4*>(p0r)[t];
  float4 v = reinterpret_cast<const float4*>(yr)[t];
  v.x += aa.x; v.y += aa.y; v.z += aa.z; v.w += aa.w;

  float s  = v.x + v.y + v.z + v.w;
  float sq = v.x * v.x + v.y * v.y + v.z * v.z + v.w * v.w;
#pragma unroll
  for (int off = 32; off > 0; off >>= 1) {
    s  += __shfl_down(s, off);
    sq += __shfl_down(sq, off);
  }
  __shared__ float red[8];
  const int wv = t >> 6, lane = t & 63;
  if (lane == 0) { red[wv] = s; red[4 + wv] = sq; }
  __syncthreads();
  if (t == 0) {
    const float S = red[0] + red[1] + red[2] + red[3];
    const float Q = red[4] + red[5] + red[6] + red[7];
    const float mu = S * (1.0f / NOUT);
    const float var = Q * (1.0f / NOUT) - mu * mu;
    red[0] = mu;
    red[1] = rsqrtf(var + 1e-5f);
  }
  __syncthreads();
  const float mu = red[0], rs = red[1];
  const float aP = pa[0];
  const float4 g4 = reinterpret_cast<const float4*>(gamma)[t];
  const float4 b4 = reinterpret_cast<const float4*>(beta)[t];
  float o0 = (v.x - mu) * rs * g4.x + b4.x;
  float o1 = (v.y - mu) * rs * g4.y + b4.y;
  float o2 = (v.z - mu) * rs * g4.z + b4.z;
  float o3 = (v.w - mu) * rs * g4.w + b4.w;
  v.x = o0 >= 0.0f ? o0 : aP * o0;
  v.y = o1 >= 0.0f ? o1 : aP * o1;
  v.z = o2 >= 0.0f ? o2 : aP * o2;
  v.w = o3 >= 0.0f ? o3 : aP * o3;
  reinterpret_cast<float4*>(yr)[t] = v;
}

// ---------------------------------------------------------------------------
extern "C" void kernel_launch(void* const* d_in, const int* in_sizes, int n_in,
                              void* d_out, int out_size, void* d_ws, size_t ws_size,
                              hipStream_t stream) {
  const float* x     = (const float*)d_in[0];
  const float* bw    = (const float*)d_in[1];
  const float* sw    = (const float*)d_in[2];
  const float* grid  = (const float*)d_in[3];
  const float* gamma = (const float*)d_in[4];
  const float* beta  = (const float*)d_in[5];
  const float* pa    = (const float*)d_in[6];
  float* out = (float*)d_out;

  __hip_bfloat16* Abuf = (__hip_bfloat16*)d_ws;                 // 8192 x 9216 bf16
  __hip_bfloat16* Wbuf = Abuf + (size_t)NB * KTOT;              // 1024 x 9216 bf16 (flat)
  float* P0 = (float*)(Wbuf + (size_t)NOUT * KTOT);             // 8192 x 1024 f32

  prep<<<4096 + 4608, 256, 0, stream>>>(x, grid, Abuf, bw, sw, Wbuf);
  gemm_flat<<<(NB / 256) * (NOUT / 256) * 2, 512, 0, stream>>>(Abuf, Wbuf, P0, out);
  reduce_ln_prelu<<<NB, 256, 0, stream>>>(P0, out, gamma, beta, pa);
}

// Round 13
// 197.406 us; speedup vs baseline: 1.2494x; 1.0500x over previous
//
#include <hip/hip_runtime.h>
#include <hip/hip_bf16.h>

typedef __attribute__((ext_vector_type(8))) short bf16x8;   // 8 bf16 (4 VGPRs)
typedef __attribute__((ext_vector_type(4))) float f32x4;    // MFMA C/D

#define KTOT 9216   // 1024 (gelu part) + 1024*8 (spline bases part)
#define KHALF 4608  // split-K slice
#define NB   8192
#define NIN  1024
#define NOUT 1024

__device__ __forceinline__ void load_lds16(const void* g, void* l) {
  __builtin_amdgcn_global_load_lds(
      (const __attribute__((address_space(1))) void*)g,
      (__attribute__((address_space(3))) void*)l, 16, 0, 0);
}

// ---------------------------------------------------------------------------
// Kernel 1 (merged prep, R8-proven): blocks [0,4096) build full A;
// blocks [4096,8704) pack W.
// ---------------------------------------------------------------------------
__global__ void prep(const float* __restrict__ x,
                     const float* __restrict__ grid,
                     __hip_bfloat16* __restrict__ A,
                     const float* __restrict__ bw,
                     const float* __restrict__ sw,
                     __hip_bfloat16* __restrict__ W) {
  if (blockIdx.x < 4096) {
    const int tid = blockIdx.x * blockDim.x + threadIdx.x;
    const int i  = tid & (NIN - 1);
    const int b0 = (tid >> 10) << 3;                       // 8 rows / thread

    float g[12];
#pragma unroll
    for (int j = 0; j < 12; ++j) g[j] = grid[j];

    float invdr1[10], invdd1[10], invdr2[9], invdd2[9], invdr3[8], invdd3[8];
#pragma unroll
    for (int j = 0; j < 10; ++j) {
      invdr1[j] = __builtin_amdgcn_rcpf(g[j + 1] - g[j]);
      invdd1[j] = __builtin_amdgcn_rcpf(g[j + 2] - g[j + 1]);
    }
#pragma unroll
    for (int j = 0; j < 9; ++j) {
      invdr2[j] = __builtin_amdgcn_rcpf(g[j + 2] - g[j]);
      invdd2[j] = __builtin_amdgcn_rcpf(g[j + 3] - g[j + 1]);
    }
#pragma unroll
    for (int j = 0; j < 8; ++j) {
      invdr3[j] = __builtin_amdgcn_rcpf(g[j + 3] - g[j]);
      invdd3[j] = __builtin_amdgcn_rcpf(g[j + 4] - g[j + 1]);
    }

    for (int bb = 0; bb < 8; ++bb) {
      const int b = b0 + bb;
      const float xv = x[(size_t)b * NIN + i];
      const float ge = 0.5f * xv * (1.0f + erff(xv * 0.70710678118654752f));
      __hip_bfloat16* Arow = A + (size_t)b * KTOT;
      Arow[i] = __float2bfloat16(ge);

      float bas[11];
#pragma unroll
      for (int j = 0; j < 11; ++j)
        bas[j] = (xv >= g[j] && xv < g[j + 1]) ? 1.0f : 0.0f;
#pragma unroll
      for (int j = 0; j < 10; ++j)
        bas[j] = (xv - g[j]) * invdr1[j] * bas[j] + (g[j + 2] - xv) * invdd1[j] * bas[j + 1];
#pragma unroll
      for (int j = 0; j < 9; ++j)
        bas[j] = (xv - g[j]) * invdr2[j] * bas[j] + (g[j + 3] - xv) * invdd2[j] * bas[j + 1];
#pragma unroll
      for (int j = 0; j < 8; ++j)
        bas[j] = (xv - g[j]) * invdr3[j] * bas[j] + (g[j + 4] - xv) * invdd3[j] * bas[j + 1];

      union { __hip_bfloat16 h[8]; uint4 v; } u;
#pragma unroll
      for (int k = 0; k < 8; ++k) u.h[k] = __float2bfloat16(bas[k]);
      *reinterpret_cast<uint4*>(Arow + NIN + i * 8) = u.v;
    }
  } else {
    const int idx = (blockIdx.x - 4096) * blockDim.x + threadIdx.x;
    const int o  = idx / 1152;
    const int c8 = (idx - o * 1152) * 8;
    const float* src = (c8 < 1024) ? (bw + (size_t)o * 1024 + c8)
                                   : (sw + (size_t)o * 8192 + (c8 - 1024));
    float4 f0 = reinterpret_cast<const float4*>(src)[0];
    float4 f1 = reinterpret_cast<const float4*>(src)[1];
    union { __hip_bfloat16 h[8]; uint4 v; } u;
    u.h[0] = __float2bfloat16(f0.x); u.h[1] = __float2bfloat16(f0.y);
    u.h[2] = __float2bfloat16(f0.z); u.h[3] = __float2bfloat16(f0.w);
    u.h[4] = __float2bfloat16(f1.x); u.h[5] = __float2bfloat16(f1.y);
    u.h[6] = __float2bfloat16(f1.z); u.h[7] = __float2bfloat16(f1.w);
    *reinterpret_cast<uint4*>(W + (size_t)o * KTOT + c8) = u.v;
  }
}

// ---------------------------------------------------------------------------
// Kernel 2: 2-barrier-per-tile GEMM. 256x256 tile, BK=64, split-K=2,
// 8 waves (2M x 4N). A ring-3 (96 KB) + B ring-2 (64 KB) = 160 KB dynamic.
// Per tile T:
//   PH-A: reads A(T)h0 (8 b128) + B(T) both halves (8 b128); stage B(T+1)
//         [4 gload_lds]; barrier; lgkmcnt(0); sched_barrier; 32 MFMA (q00,q01)
//   PH-B: reads A(T)h1 (8 b128); stage A(T+2) [4]; vmcnt(4); barrier;
//         lgkmcnt(0); sched_barrier; 32 MFMA (q11,q10)
// Drain audit (steady): pool at VM_b(T) = {A(T+1) 4 [PH-B(T-1)], B(T+1) 4
// [PH-A(T)], A(T+2) 4 [PH-B(T)]}; vmcnt(4) drains A(T+1)+B(T+1) — exactly
// what tile T+1's reads need; published by PH-B(T) barrier. No other gate
// needed. Overwrite safety: B(T+1) overwrites B(T-1)'s slot, whose reads
// (PH-A(T-1)) drained before each wave reached the PH-B(T-1) barrier that
// precedes the staging wave's issue; A(T+2) overwrites A(T-1), whose h1
// reads (PH-B(T-1)) drained before the PH-A(T) barrier. Both >= 1 barrier.
// Prologue {A(0),B(0),A(1)} + vmcnt(4). Tail: VM_b(70)=vmcnt(0); 71 none.
// ---------------------------------------------------------------------------
__global__ __launch_bounds__(512, 2)
void gemm_2b(const __hip_bfloat16* __restrict__ A,
             const __hip_bfloat16* __restrict__ Bw,
             float* __restrict__ P0,
             float* __restrict__ P1w) {
  extern __shared__ char smem[];   // 160 KB: A[3][2][64r][128B] + B[2][...]

  const int tid  = threadIdx.x;
  const int lane = tid & 63;
  const int wave = tid >> 6;
  const int wr = wave >> 2;          // 0..1 -> M half (128 rows)
  const int wc = wave & 3;           // 0..3 -> N quarter (64 cols)

  const int orig = blockIdx.x;                    // 256 blocks
  const int bid  = (orig & 7) * 32 + (orig >> 3); // bijective XCD chunking
  const int ks    = bid & 1;                      // K slice
  const int tileN = (bid >> 1) & 3;               // 4 N tiles
  const int tileM = bid >> 3;                     // 32 M tiles
  const size_t brow = (size_t)tileM * 256;
  const size_t bcol = (size_t)tileN * 256;
  const int kbeg = ks * KHALF;

  const __hip_bfloat16* Ab = A  + brow * KTOT;
  const __hip_bfloat16* Bb = Bw + bcol * KTOT;
  float* C = ks ? P1w : P0;

  // ---- staging (pre-swizzled global source, linear LDS dest) ----
  const int swsrc = ((tid & 7) ^ ((tid >> 3) & 7)) * 8;
  const __hip_bfloat16* srcA = Ab + (size_t)(tid >> 3) * KTOT + kbeg + swsrc;
  const __hip_bfloat16* srcB = Bb + (size_t)(tid >> 3) * KTOT + kbeg + swsrc;
  const int wdst = wave * 1024;

#define AB_(buf)  (smem + (buf) * 32768)            // A ring-3
#define BB_(slot) (smem + 98304 + (slot) * 32768)   // B ring-2

  auto stageA = [&](int buf, int h, int kt) {
    const __hip_bfloat16* g = srcA + (size_t)h * (128 * KTOT) + (size_t)kt * 64;
    char* d = AB_(buf) + h * 16384 + wdst;
    load_lds16(g, d);
    load_lds16(g + (size_t)64 * KTOT, d + 8192);
  };
  auto stageB = [&](int slot, int h, int kt) {
    const __hip_bfloat16* g = srcB + (size_t)h * (128 * KTOT) + (size_t)kt * 64;
    char* d = BB_(slot) + h * 16384 + wdst;
    load_lds16(g, d);
    load_lds16(g + (size_t)64 * KTOT, d + 8192);
  };

  // ---- fragment read addressing (XOR term is a per-lane constant) ----
  const int fr = lane & 15;
  const int hi = lane >> 4;                      // 0..3 -> k-slot within 32
  const int sw = (fr & 7) << 4;
  const int ax0 = (hi * 16) ^ sw;                // kk=0 slot byte
  const int ax1 = (64 + hi * 16) ^ sw;           // kk=1 slot byte

  bf16x8 a[4][2], b[4][2];
  f32x4 acc[8][4] = {};

#define RD_A(BUF, MH) { \
    const char* Ah = AB_(BUF) + wr * 16384 + (MH) * 8192; \
    _Pragma("unroll") \
    for (int mi2 = 0; mi2 < 4; ++mi2) { \
      const char* p = Ah + (mi2 * 16 + fr) * 128; \
      a[mi2][0] = *(const bf16x8*)(p + ax0); \
      a[mi2][1] = *(const bf16x8*)(p + ax1); } }

#define RD_B(SLOT, NH) { \
    const char* Bh = BB_(SLOT) + (wc >> 1) * 16384 + ((wc & 1) * 64 + (NH) * 32) * 128; \
    _Pragma("unroll") \
    for (int ni2 = 0; ni2 < 2; ++ni2) { \
      const char* p = Bh + (ni2 * 16 + fr) * 128; \
      b[(NH) * 2 + ni2][0] = *(const bf16x8*)(p + ax0); \
      b[(NH) * 2 + ni2][1] = *(const bf16x8*)(p + ax1); } }

// barrier first, then drain this wave's ds ops (reads cross the barrier);
// sched_barrier stops MFMA hoisting above the lgkm wait (rule 18).
#define PH_SYNC() do { \
    asm volatile("" ::: "memory"); \
    __builtin_amdgcn_s_barrier(); \
    asm volatile("s_waitcnt lgkmcnt(0)" ::: "memory"); \
    __builtin_amdgcn_sched_barrier(0); } while (0)

#define QMFMA(MH, NH) do { \
    __builtin_amdgcn_s_setprio(1); \
    _Pragma("unroll") \
    for (int mi2 = 0; mi2 < 4; ++mi2) \
      _Pragma("unroll") \
      for (int ni2 = 0; ni2 < 2; ++ni2) \
        _Pragma("unroll") \
        for (int kk = 0; kk < 2; ++kk) \
          acc[(MH) * 4 + mi2][(NH) * 2 + ni2] = \
            __builtin_amdgcn_mfma_f32_16x16x32_bf16(a[mi2][kk], b[(NH) * 2 + ni2][kk], \
                                                    acc[(MH) * 4 + mi2][(NH) * 2 + ni2], 0, 0, 0); \
    __builtin_amdgcn_s_setprio(0); } while (0)

#define TILE(T, ABUF, A2, BSL, STB, STA, VMB) do { \
    /* PH-A */ \
    RD_A(ABUF, 0); RD_B(BSL, 0); RD_B(BSL, 1); \
    if (STB) { stageB((BSL) ^ 1, 0, (T) + 1); stageB((BSL) ^ 1, 1, (T) + 1); } \
    PH_SYNC(); \
    QMFMA(0, 0); QMFMA(0, 1); \
    /* PH-B */ \
    RD_A(ABUF, 1); \
    if (STA) { stageA(A2, 0, (T) + 2); stageA(A2, 1, (T) + 2); } \
    asm volatile(VMB ::: "memory"); \
    PH_SYNC(); \
    QMFMA(1, 1); QMFMA(1, 0); \
  } while (0)

  // prologue: A(0) 4, B(0) 4, A(1) 4; vmcnt(4) drains A(0)+B(0); publish.
  stageA(0, 0, 0); stageA(0, 1, 0);
  stageB(0, 0, 0); stageB(0, 1, 0);
  stageA(1, 0, 1); stageA(1, 1, 1);
  asm volatile("s_waitcnt vmcnt(4)" ::: "memory");
  __builtin_amdgcn_s_barrier();
  asm volatile("" ::: "memory");

  // main: T = 0..65 (11 iters x 6, period lcm(3,2)=6), steady vmcnt(4)
  for (int it = 0; it < 11; ++it) {
    const int t0 = it * 6;
    TILE(t0 + 0, 0, 2, 0, 1, 1, "s_waitcnt vmcnt(4)");
    TILE(t0 + 1, 1, 0, 1, 1, 1, "s_waitcnt vmcnt(4)");
    TILE(t0 + 2, 2, 1, 0, 1, 1, "s_waitcnt vmcnt(4)");
    TILE(t0 + 3, 0, 2, 1, 1, 1, "s_waitcnt vmcnt(4)");
    TILE(t0 + 4, 1, 0, 0, 1, 1, "s_waitcnt vmcnt(4)");
    TILE(t0 + 5, 2, 1, 1, 1, 1, "s_waitcnt vmcnt(4)");
  }
  // tail: T = 66..71 (last A stage at T=69 -> A(71); last B at T=70 -> B(71))
  TILE(66, 0, 2, 0, 1, 1, "s_waitcnt vmcnt(4)");
  TILE(67, 1, 0, 1, 1, 1, "s_waitcnt vmcnt(4)");
  TILE(68, 2, 1, 0, 1, 1, "s_waitcnt vmcnt(4)");
  TILE(69, 0, 2, 1, 1, 1, "s_waitcnt vmcnt(4)");
  TILE(70, 1, 0, 0, 1, 0, "s_waitcnt vmcnt(0)");
  TILE(71, 2, 1, 1, 0, 0, "s_nop 0");

#undef TILE
#undef QMFMA
#undef PH_SYNC
#undef RD_B
#undef RD_A
#undef BB_
#undef AB_

  // epilogue: C/D layout col = lane&15, row = (lane>>4)*4 + reg
  const int crow0 = (lane >> 4) * 4;
#pragma unroll
  for (int mi = 0; mi < 8; ++mi)
#pragma unroll
    for (int ni = 0; ni < 4; ++ni) {
      const size_t r0 = brow + wr * 128 + mi * 16 + crow0;
      const size_t cc = bcol + wc * 64 + ni * 16 + fr;
      float* cp = C + r0 * NOUT + cc;
#pragma unroll
      for (int r = 0; r < 4; ++r) cp[(size_t)r * NOUT] = acc[mi][ni][r];
    }
}

// ---------------------------------------------------------------------------
// Kernel 3: y = P0 + P1 (split-K reduce), rowwise LayerNorm + PReLU -> y.
// P1 aliases d_out. One block per row.
// ---------------------------------------------------------------------------
__global__ void reduce_ln_prelu(const float* __restrict__ P0,
                                float* __restrict__ y,
                                const float* __restrict__ gamma,
                                const float* __restrict__ beta,
                                const float* __restrict__ pa) {
  const int row = blockIdx.x;
  const int t = threadIdx.x;                 // 256 threads, 4 floats each
  const float* p0r = P0 + (size_t)row * NOUT;
  float* yr = y + (size_t)row * NOUT;

  float4 aa = reinterpret_cast<const float4*>(p0r)[t];
  float4 v = reinterpret_cast<const float4*>(yr)[t];
  v.x += aa.x; v.y += aa.y; v.z += aa.z; v.w += aa.w;

  float s  = v.x + v.y + v.z + v.w;
  float sq = v.x * v.x + v.y * v.y + v.z * v.z + v.w * v.w;
#pragma unroll
  for (int off = 32; off > 0; off >>= 1) {
    s  += __shfl_down(s, off);
    sq += __shfl_down(sq, off);
  }
  __shared__ float red[8];
  const int wv = t >> 6, lane = t & 63;
  if (lane == 0) { red[wv] = s; red[4 + wv] = sq; }
  __syncthreads();
  if (t == 0) {
    const float S = red[0] + red[1] + red[2] + red[3];
    const float Q = red[4] + red[5] + red[6] + red[7];
    const float mu = S * (1.0f / NOUT);
    const float var = Q * (1.0f / NOUT) - mu * mu;
    red[0] = mu;
    red[1] = rsqrtf(var + 1e-5f);
  }
  __syncthreads();
  const float mu = red[0], rs = red[1];
  const float aP = pa[0];
  const float4 g4 = reinterpret_cast<const float4*>(gamma)[t];
  const float4 b4 = reinterpret_cast<const float4*>(beta)[t];
  float o0 = (v.x - mu) * rs * g4.x + b4.x;
  float o1 = (v.y - mu) * rs * g4.y + b4.y;
  float o2 = (v.z - mu) * rs * g4.z + b4.z;
  float o3 = (v.w - mu) * rs * g4.w + b4.w;
  v.x = o0 >= 0.0f ? o0 : aP * o0;
  v.y = o1 >= 0.0f ? o1 : aP * o1;
  v.z = o2 >= 0.0f ? o2 : aP * o2;
  v.w = o3 >= 0.0f ? o3 : aP * o3;
  reinterpret_cast<float4*>(yr)[t] = v;
}

// ---------------------------------------------------------------------------
extern "C" void kernel_launch(void* const* d_in, const int* in_sizes, int n_in,
                              void* d_out, int out_size, void* d_ws, size_t ws_size,
                              hipStream_t stream) {
  const float* x     = (const float*)d_in[0];
  const float* bw    = (const float*)d_in[1];
  const float* sw    = (const float*)d_in[2];
  const float* grid  = (const float*)d_in[3];
  const float* gamma = (const float*)d_in[4];
  const float* beta  = (const float*)d_in[5];
  const float* pa    = (const float*)d_in[6];
  float* out = (float*)d_out;

  __hip_bfloat16* Abuf = (__hip_bfloat16*)d_ws;                 // 8192 x 9216 bf16
  __hip_bfloat16* Wbuf = Abuf + (size_t)NB * KTOT;              // 1024 x 9216 bf16
  float* P0 = (float*)(Wbuf + (size_t)NOUT * KTOT);             // 8192 x 1024 f32

  // allow 160 KB dynamic LDS for the GEMM (idempotent, capture-safe)
  hipFuncSetAttribute(reinterpret_cast<const void*>(gemm_2b),
                      hipFuncAttributeMaxDynamicSharedMemorySize, 163840);

  prep<<<4096 + 4608, 256, 0, stream>>>(x, grid, Abuf, bw, sw, Wbuf);
  gemm_2b<<<(NB / 256) * (NOUT / 256) * 2, 512, 163840, stream>>>(Abuf, Wbuf, P0, out);
  reduce_ln_prelu<<<NB, 256, 0, stream>>>(P0, out, gamma, beta, pa);
}